// Round 14
// baseline (275.030 us; speedup 1.0000x reference)
//
#include <hip/hip_runtime.h>
#include <hip/hip_bf16.h>
#include <stdint.h>

#define NN 100000
#define NE 1600000
#define NBLK 256                 // edge-chunk blocks for hist/scatter
#define EPB (NE / NBLK)          // 6250 edges per block
#define NBINS 782                // ceil(NN/128) coarse bins of 128 nodes
#define NCELL (NBINS * NBLK)     // 200192 scan cells
#define NSB ((NCELL + 1023) / 1024)  // 196 scan blocks
#define GEMMB 1563               // gemm blocks: 64 rows per block
#define BINCAP 4096              // LDS cache per bin (mean bin count 2046, sd ~45)
#define SMEM_BYTES (BINCAP * 4 + 3 * 128 * 4)   // 17920 B; also >= 64*65*4 = 16640

// ---------------- bf16 helpers ----------------

__device__ __forceinline__ unsigned pack_bf16(float a, float b) {
    unsigned ua = __float_as_uint(a);
    unsigned ub = __float_as_uint(b);
    ua += 0x7FFFu + ((ua >> 16) & 1u);       // RNE
    ub += 0x7FFFu + ((ub >> 16) & 1u);
    return (ua >> 16) | (ub & 0xFFFF0000u);  // a -> low half (element 2k)
}
#define BF_LO(u) __uint_as_float((u) << 16)
#define BF_HI(u) __uint_as_float((u) & 0xFFFF0000u)

// ---------------- edge_index width detection, inlined ----------------------

__device__ __forceinline__ int ei_is64(const int* __restrict__ ei) {
    int z = 0;
#pragma unroll
    for (int i = 0; i < 16; ++i) z |= ei[2 * i + 1];
    return z == 0;
}

// ---------------- CSR build via 2-level counting sort (NO global atomics) ----
// R4: global atomic-return fill = 160us (coherence serialization). R8: fused
// grid-barrier build = 126us (cross-XCD spin). Split 4-kernel counting sort
// is the verified design.

__global__ void __launch_bounds__(1024) k_hist(const int* __restrict__ ei,
                                               int* __restrict__ gcount) {
    __shared__ int lbin[NBINS];
    int t = threadIdx.x, blk = blockIdx.x;
    for (int i = t; i < NBINS; i += 1024) lbin[i] = 0;
    __syncthreads();
    int is64 = ei_is64(ei);
    int e0 = blk * EPB;
    if (is64) {
        const int2* p = (const int2*)ei;
        for (int e = e0 + t; e < e0 + EPB; e += 1024)
            atomicAdd(&lbin[p[NE + e].x >> 7], 1);
    } else {
        for (int e = e0 + t; e < e0 + EPB; e += 1024)
            atomicAdd(&lbin[ei[NE + e] >> 7], 1);
    }
    __syncthreads();
    for (int b = t; b < NBINS; b += 1024) gcount[b * NBLK + blk] = lbin[b];
}

__global__ void k_pscan1(const int* __restrict__ g, int* __restrict__ bsum) {
    __shared__ int sh[256];
    int t = threadIdx.x;
    int base = blockIdx.x * 1024 + t * 4;
    int s = 0;
#pragma unroll
    for (int j = 0; j < 4; ++j) { int i = base + j; if (i < NCELL) s += g[i]; }
    sh[t] = s; __syncthreads();
    for (int off = 128; off > 0; off >>= 1) {
        if (t < off) sh[t] += sh[t + off];
        __syncthreads();
    }
    if (t == 0) bsum[blockIdx.x] = sh[0];
}

// pscan2 fused into pscan3: each block redundantly scans the 196 block sums
// (784 B, trivial) to find its own offset -> one fewer dependent launch.
__global__ void k_pscan23(const int* __restrict__ g, const int* __restrict__ bsum,
                          int* __restrict__ goff) {
    __shared__ int sh[256];
    __shared__ int boffs;
    int t = threadIdx.x;
    int bv = (t < NSB) ? bsum[t] : 0;
    sh[t] = bv; __syncthreads();
    for (int off = 1; off < 256; off <<= 1) {
        int tmp = (t >= off) ? sh[t - off] : 0;
        __syncthreads();
        sh[t] += tmp;
        __syncthreads();
    }
    if (t == blockIdx.x) boffs = sh[t] - bv;   // exclusive prefix of own block
    __syncthreads();
    int base = blockIdx.x * 1024 + t * 4;
    int v[4]; int s = 0;
#pragma unroll
    for (int j = 0; j < 4; ++j) { int i = base + j; v[j] = (i < NCELL) ? g[i] : 0; s += v[j]; }
    __syncthreads();                           // sh reuse safe (scan loop done)
    sh[t] = s; __syncthreads();
    for (int off = 1; off < 256; off <<= 1) {
        int tmp = (t >= off) ? sh[t - off] : 0;
        __syncthreads();
        sh[t] += tmp;
        __syncthreads();
    }
    int run = sh[t] - s + boffs;
#pragma unroll
    for (int j = 0; j < 4; ++j) {
        int i = base + j;
        if (i < NCELL) { goff[i] = run; run += v[j]; }
    }
}

// ---------------- scatter, R13-verified: two-phase LDS-sorted, ORDERED writes
// (was 6x write amplification from 64 scattered 4B partial lines per store;
// ordered pass emits each cell's ~8 entries as one 32B run). R13: -12us.
// tmp entry: src (17 bits) | d_low7 << 17.

__global__ void __launch_bounds__(1024) k_scatter(const int* __restrict__ ei,
                                                  const int* __restrict__ gcount,
                                                  const int* __restrict__ goff,
                                                  unsigned* __restrict__ tmp) {
    __shared__ int gbase[NBINS];
    __shared__ int lofs[NBINS];
    __shared__ int lcur[NBINS];
    __shared__ int sc[1024];
    __shared__ uint2 buf[EPB];      // 50 KB; total LDS 63.5 KB, 2 blocks/CU
    int t = threadIdx.x, blk = blockIdx.x;
    int c = 0;
    if (t < NBINS) {
        c = gcount[t * NBLK + blk];
        gbase[t] = goff[t * NBLK + blk];
    }
    sc[t] = c;
    __syncthreads();
    for (int off = 1; off < 1024; off <<= 1) {     // inclusive scan, 1 thr/bin
        int v = (t >= off) ? sc[t - off] : 0;
        __syncthreads();
        sc[t] += v;
        __syncthreads();
    }
    if (t < NBINS) {
        int ex = sc[t] - c;        // exclusive prefix = this bin's local base
        lofs[t] = ex;
        lcur[t] = ex;
    }
    __syncthreads();
    int is64 = ei_is64(ei);
    int e0 = blk * EPB;
    for (int e = e0 + t; e < e0 + EPB; e += 1024) {
        int s, d;
        if (is64) {
            s = ((const int2*)ei)[e].x;
            d = ((const int2*)ei)[NE + e].x;
        } else {
            s = ei[e];
            d = ei[NE + e];
        }
        int b = d >> 7;
        int li = atomicAdd(&lcur[b], 1);
        unsigned pos = (unsigned)(gbase[b] + (li - lofs[b]));
        buf[li] = make_uint2(pos, (unsigned)s | ((unsigned)(d & 127) << 17));
    }
    __syncthreads();
    for (int i = t; i < EPB; i += 1024)            // ordered write pass
        tmp[buf[i].x] = buf[i].y;
}

// ---------------- fp32 GEMM -> bf16 H: H[N,64] = X[N,64] @ W[64,64] ----------
// R11-verified: lane=row compute mapping (wave-uniform W -> s_load, acc[] in
// VGPRs) + X tile staged through LDS with one coalesced block load, padded
// [64][65] so per-lane row reads are bank-rotated conflict-free. Block =
// 4 waves = 4 column-quarters of one 64-row tile. Bit-identical k-order.
// (Used for layer-1 via the degcsr co-launch; layer-2 gemm is fused into
// k_agg_gemm as of R14.)

__device__ __forceinline__ void gemm_body(int gb, const float* __restrict__ X,
                                          const float* __restrict__ W,
                                          unsigned* __restrict__ Hb,
                                          float* xt) {
    int t = threadIdx.x;
    int lane = t & 63;
    int wv = t >> 6;                      // column quarter 0..3
    int rbase = gb * 64;
    const float4* xg = (const float4*)X;
#pragma unroll
    for (int j = 0; j < 4; ++j) {
        int idx = j * 256 + t;            // 0..1023 = 64 rows x 16 float4
        int row = idx >> 4;
        int q = idx & 15;
        int gr = rbase + row;
        int r = gr < NN ? gr : NN - 1;    // clamped rows stage duplicate data
        float4 v = xg[(size_t)r * 16 + q];
        float* dst = xt + row * 65 + q * 4;
        dst[0] = v.x; dst[1] = v.y; dst[2] = v.z; dst[3] = v.w;
    }
    __syncthreads();
    int grow = rbase + lane;
    int r = grow < NN ? grow : NN - 1;
    int ch = __builtin_amdgcn_readfirstlane(wv);   // scalar -> W via s_load
    const float* Wb = W + ch * 16;                 // columns ch*16 .. ch*16+15
    const float* xr = xt + lane * 65;
    float acc[16];
#pragma unroll
    for (int c = 0; c < 16; ++c) acc[c] = 0.f;
#pragma unroll 4
    for (int k4 = 0; k4 < 16; ++k4) {
#pragma unroll
        for (int kj = 0; kj < 4; ++kj) {
            float xk = xr[k4 * 4 + kj];
            const float4* wr = (const float4*)(Wb + (k4 * 4 + kj) * 64);
#pragma unroll
            for (int c4 = 0; c4 < 4; ++c4) {
                float4 wv4 = wr[c4];
                acc[c4 * 4 + 0] += xk * wv4.x;
                acc[c4 * 4 + 1] += xk * wv4.y;
                acc[c4 * 4 + 2] += xk * wv4.z;
                acc[c4 * 4 + 3] += xk * wv4.w;
            }
        }
    }
    // store 16 bf16 = 8 words = 2 uint4 at row base + quarter offset
    uint4* op = (uint4*)(Hb + (size_t)r * 32 + ch * 8);
#pragma unroll
    for (int q = 0; q < 2; ++q) {
        uint4 o;
        o.x = pack_bf16(acc[q * 8 + 0], acc[q * 8 + 1]);
        o.y = pack_bf16(acc[q * 8 + 2], acc[q * 8 + 3]);
        o.z = pack_bf16(acc[q * 8 + 4], acc[q * 8 + 5]);
        o.w = pack_bf16(acc[q * 8 + 6], acc[q * 8 + 7]);
        op[q] = o;
    }
}

// ---------------- fused deg+csr (single tmp pass, LDS-cached) + gemm1 -------
// Blocks [0,NBINS): finalize CSR for one 128-node bin (tmp streamed once,
// LDS-cached). csr entry is just the src id; per-edge weight is gathered as
// dinv[src] in k_agg. Blocks [NBINS,NBINS+GEMMB): layer-1 GEMM co-launched.
// One shared buffer reinterpreted by both branches -> LDS stays 17.9 KB.

__global__ void __launch_bounds__(256) k_degcsr_gemm(const unsigned* __restrict__ tmp,
                                                     const int* __restrict__ goff,
                                                     int* __restrict__ rs,
                                                     float* __restrict__ dinv,
                                                     unsigned* __restrict__ csr,
                                                     const float* __restrict__ X,
                                                     const float* __restrict__ W1,
                                                     unsigned* __restrict__ Hb) {
    __shared__ __align__(16) char smem[SMEM_BYTES];
    if (blockIdx.x >= NBINS) {
        gemm_body((int)blockIdx.x - NBINS, X, W1, Hb, (float*)smem);
        return;
    }
    unsigned* cache  = (unsigned*)smem;
    int*      hist   = (int*)(smem + BINCAP * 4);
    int*      cur    = hist + 128;
    int*      base_sh= cur + 128;
    int b = blockIdx.x, t = threadIdx.x;
    if (t < 128) { hist[t] = 0; cur[t] = 0; }
    __syncthreads();
    int bs = goff[b * NBLK];
    int be = (b == NBINS - 1) ? NE : goff[(b + 1) * NBLK];
    for (int e = bs + t; e < be; e += 256) {
        unsigned v = tmp[e];
        int i = e - bs;
        if (i < BINCAP) cache[i] = v;
        atomicAdd(&hist[v >> 17], 1);
    }
    __syncthreads();
    if (t < 128) {
        int node = b * 128 + t;
        if (node < NN) {
            int c = hist[t];
            int loff = 0;
            for (int i = 0; i < t; ++i) loff += hist[i];
            rs[node] = bs + loff;
            base_sh[t] = bs + loff;
            dinv[node] = rsqrtf((float)c + 1.0f);
        } else base_sh[t] = 0;
    }
    if (b == 0 && t == 0) rs[NN] = NE;
    __syncthreads();
    int cnt = be - bs;
    for (int i = t; i < cnt; i += 256) {
        unsigned v = (i < BINCAP) ? cache[i] : tmp[bs + i];
        int dl = v >> 17;
        int lr = atomicAdd(&cur[dl], 1);
        csr[base_sh[dl] + lr] = v & 0x1FFFFu;   // plain src id
    }
}

// ---------------- aggregation gather body (R11-frozen structure) ------------
// R6 (uint2), R7 (per-lane fused gemm), R12 (batch-16 masking) all regressed:
// half-wave h owns node 2*wid+h, 4 edge groups x 8 feature lanes, uint4 16B
// gathers, 2-deep csr pipeline, 2-level reduce. After AGG_REDUCE, lanes with
// (lane&31)<8 hold the node's aggregated sums a0..a7 for feature octet s.

#define EDGE_ACC(wt, r)                                                       \
    {                                                                         \
        a0 += BF_LO((r).x) * (wt); a1 += BF_HI((r).x) * (wt);                 \
        a2 += BF_LO((r).y) * (wt); a3 += BF_HI((r).y) * (wt);                 \
        a4 += BF_LO((r).z) * (wt); a5 += BF_HI((r).z) * (wt);                 \
        a6 += BF_LO((r).w) * (wt); a7 += BF_HI((r).w) * (wt);                 \
    }

#define AGG_GATHER_REDUCE(hb_, rs_, csr_, dinv_)                              \
    int wid = (blockIdx.x * blockDim.x + threadIdx.x) >> 6;                   \
    int lane = threadIdx.x & 63;                                              \
    int node = wid * 2 + (lane >> 5);          /* half-wave owns one node */  \
    if (node >= NN) return;                    /* never taken: exact grid */  \
    int g = (lane >> 3) & 3;                                                  \
    int s = lane & 7;                                                         \
    const char* hbc = (const char*)(hb_);                                     \
    const char* dvc = (const char*)(dinv_);                                   \
    unsigned soff = (unsigned)s << 4;                                         \
    float dn = (dinv_)[node];                                                 \
    int e0 = (rs_)[node], e1 = (rs_)[node + 1];                               \
    float a0 = 0.f, a1 = 0.f, a2 = 0.f, a3 = 0.f;                             \
    float a4 = 0.f, a5 = 0.f, a6 = 0.f, a7 = 0.f;                             \
    int e = e0 + g;                                                           \
    unsigned p0 = (csr_)[e];                                                  \
    unsigned p1 = (csr_)[e + 4];                                              \
    for (; e + 4 < e1; e += 8) {                                              \
        unsigned q0 = (csr_)[e + 8];                                          \
        unsigned q1 = (csr_)[e + 12];                                         \
        float w0 = *(const float*)(dvc + (size_t)(p0 << 2));                  \
        float w1 = *(const float*)(dvc + (size_t)(p1 << 2));                  \
        uint4 r0 = *(const uint4*)(hbc + (size_t)((p0 << 7) + soff));         \
        uint4 r1 = *(const uint4*)(hbc + (size_t)((p1 << 7) + soff));         \
        EDGE_ACC(w0, r0);                                                     \
        EDGE_ACC(w1, r1);                                                     \
        p0 = q0; p1 = q1;                                                     \
    }                                                                         \
    if (e < e1) {                                                             \
        float w0 = *(const float*)(dvc + (size_t)(p0 << 2));                  \
        uint4 r0 = *(const uint4*)(hbc + (size_t)((p0 << 7) + soff));         \
        EDGE_ACC(w0, r0);                                                     \
    }                                                                         \
    _Pragma("unroll")                                                         \
    for (int m = 8; m <= 16; m <<= 1) {                                       \
        a0 += __shfl_xor(a0, m); a1 += __shfl_xor(a1, m);                     \
        a2 += __shfl_xor(a2, m); a3 += __shfl_xor(a3, m);                     \
        a4 += __shfl_xor(a4, m); a5 += __shfl_xor(a5, m);                     \
        a6 += __shfl_xor(a6, m); a7 += __shfl_xor(a7, m);                     \
    }

// layer-2 aggregation: epilogue writes relu(... + b2) as fp32 to d_out.
__global__ void __launch_bounds__(256) k_agg(const unsigned* __restrict__ hb,
                                             const int* __restrict__ rs,
                                             const unsigned* __restrict__ csr,
                                             const float* __restrict__ dinv,
                                             const float* __restrict__ bias,
                                             float4* __restrict__ out4) {
    AGG_GATHER_REDUCE(hb, rs, csr, dinv)
    if ((lane & 31) < 8) {
        uint4 r = *(const uint4*)(hbc + (size_t)(((unsigned)node << 7) + soff));
        const float4* bp = (const float4*)(bias + s * 8);
        float4 b0 = bp[0], b1v = bp[1];
        float4 o0, o1;
        o0.x = fmaxf((a0 + BF_LO(r.x) * dn) * dn + b0.x, 0.f);
        o0.y = fmaxf((a1 + BF_HI(r.x) * dn) * dn + b0.y, 0.f);
        o0.z = fmaxf((a2 + BF_LO(r.y) * dn) * dn + b0.z, 0.f);
        o0.w = fmaxf((a3 + BF_HI(r.y) * dn) * dn + b0.w, 0.f);
        o1.x = fmaxf((a4 + BF_LO(r.z) * dn) * dn + b1v.x, 0.f);
        o1.y = fmaxf((a5 + BF_HI(r.z) * dn) * dn + b1v.y, 0.f);
        o1.z = fmaxf((a6 + BF_LO(r.w) * dn) * dn + b1v.z, 0.f);
        o1.w = fmaxf((a7 + BF_HI(r.w) * dn) * dn + b1v.w, 0.f);
        out4[(size_t)node * 16 + s * 2] = o0;
        out4[(size_t)node * 16 + s * 2 + 1] = o1;
    }
}

// ---------------- R14: layer-1 agg + BLOCK-PARALLEL fused layer-2 GEMM ------
// R7's fused attempt failed because the GEMM was a per-lane SERIAL 64-deep
// shfl+load chain. Here the block's 8 nodes' relu'd rows land in a 2KB LDS
// tile (row = t>>5 exactly), then the 8x64x64 GEMM spreads over all 256
// threads: thread = (row r = t>>5, col pair j0 = (t&31)*2), 128 FMAs each,
// W2 L1-resident (16KB), hm reads broadcast. Deletes the k_gemm2 dispatch
// and the 51MB fp32 hmid round-trip. k ascending per (row,col) — identical
// sum order to gemm_body -> bit-identical output.
__global__ void __launch_bounds__(256) k_agg_gemm(const unsigned* __restrict__ hb,
                                                  const int* __restrict__ rs,
                                                  const unsigned* __restrict__ csr,
                                                  const float* __restrict__ dinv,
                                                  const float* __restrict__ bias,
                                                  const float* __restrict__ W2,
                                                  unsigned* __restrict__ Hb2) {
    __shared__ float hm[8][64];   // block's 8 node rows, fp32 relu'd layer-1
    AGG_GATHER_REDUCE(hb, rs, csr, dinv)
    int row = threadIdx.x >> 5;   // == block-local node index 0..7
    if ((lane & 31) < 8) {
        uint4 r = *(const uint4*)(hbc + (size_t)(((unsigned)node << 7) + soff));
        const float4* bp = (const float4*)(bias + s * 8);
        float4 b0 = bp[0], b1v = bp[1];
        float* hd = &hm[row][s * 8];
        hd[0] = fmaxf((a0 + BF_LO(r.x) * dn) * dn + b0.x, 0.f);
        hd[1] = fmaxf((a1 + BF_HI(r.x) * dn) * dn + b0.y, 0.f);
        hd[2] = fmaxf((a2 + BF_LO(r.y) * dn) * dn + b0.z, 0.f);
        hd[3] = fmaxf((a3 + BF_HI(r.y) * dn) * dn + b0.w, 0.f);
        hd[4] = fmaxf((a4 + BF_LO(r.z) * dn) * dn + b1v.x, 0.f);
        hd[5] = fmaxf((a5 + BF_HI(r.z) * dn) * dn + b1v.y, 0.f);
        hd[6] = fmaxf((a6 + BF_LO(r.w) * dn) * dn + b1v.z, 0.f);
        hd[7] = fmaxf((a7 + BF_HI(r.w) * dn) * dn + b1v.w, 0.f);
    }
    __syncthreads();
    // block-parallel 8x64 @ 64x64: thread (row, col pair)
    int j0 = (threadIdx.x & 31) * 2;
    const float* hr = hm[row];
    float g0 = 0.f, g1 = 0.f;
#pragma unroll 8
    for (int k = 0; k < 64; ++k) {
        float h = hr[k];
        const float* wk = W2 + k * 64 + j0;
        g0 += h * wk[0];
        g1 += h * wk[1];
    }
    int nb = blockIdx.x * 8 + row;            // grid exact: nb < NN always
    Hb2[(size_t)nb * 32 + (threadIdx.x & 31)] = pack_bf16(g0, g1);
}

// ---------------- launch ----------------

extern "C" void kernel_launch(void* const* d_in, const int* in_sizes, int n_in,
                              void* d_out, int out_size, void* d_ws, size_t ws_size,
                              hipStream_t stream) {
    const float* x  = (const float*)d_in[0];            // [NN,64] fp32
    const int* ei   = (const int*)d_in[1];              // [2,NE] int32/int64 (detected)
    const float* W1 = (const float*)d_in[2];
    const float* b1 = (const float*)d_in[3];
    const float* W2 = (const float*)d_in[4];
    const float* b2 = (const float*)d_in[5];

    char* ws = (char*)d_ws;
    size_t off = 0;
    auto alloc = [&](size_t bytes) -> char* {
        char* p = ws + off;
        off = (off + bytes + 511) & ~(size_t)511;
        return p;
    };
    int*      gcount= (int*)alloc((size_t)NCELL * 4);    // 800 KB
    int*      goff  = (int*)alloc((size_t)NCELL * 4);    // 800 KB
    int*      bsum  = (int*)alloc((size_t)NSB * 4);
    unsigned* tmp   = (unsigned*)alloc((size_t)NE * 4);  // 6.4 MB
    unsigned* csr   = (unsigned*)alloc((size_t)NE * 4);  // 6.4 MB
    int*      rs    = (int*)alloc((size_t)(NN + 1) * 4);
    float*    dinv  = (float*)alloc((size_t)NN * 4);
    unsigned* hbuf  = (unsigned*)alloc((size_t)NN * 32 * 4);  // 12.8 MB bf16 h1
    unsigned* hbuf2 = (unsigned*)alloc((size_t)NN * 32 * 4);  // 12.8 MB bf16 h2

    k_hist<<<NBLK, 1024, 0, stream>>>(ei, gcount);
    k_pscan1<<<NSB, 256, 0, stream>>>(gcount, bsum);
    k_pscan23<<<NSB, 256, 0, stream>>>(gcount, bsum, goff);
    k_scatter<<<NBLK, 1024, 0, stream>>>(ei, gcount, goff, tmp);
    // CSR finalize + layer-1 GEMM co-launched (independent work, common consumer)
    k_degcsr_gemm<<<NBINS + GEMMB, 256, 0, stream>>>(tmp, goff, rs, dinv, csr,
                                                     x, W1, hbuf);
    // layer-1 agg + relu + block-parallel fused layer-2 GEMM -> hbuf2 (bf16)
    k_agg_gemm<<<(NN / 2) * 64 / 256, 256, 0, stream>>>(hbuf, rs, csr, dinv, b1,
                                                        W2, hbuf2);
    // layer-2 agg + relu -> d_out
    k_agg<<<(NN / 2) * 64 / 256, 256, 0, stream>>>(hbuf2, rs, csr, dinv, b2,
                                                   (float4*)d_out);
}

// Round 15
// 217.661 us; speedup vs baseline: 1.2636x; 1.2636x over previous
//
#include <hip/hip_runtime.h>
#include <hip/hip_bf16.h>
#include <stdint.h>

#define NN 100000
#define NE 1600000
#define NBLK 256                 // edge-chunk blocks for hist/scatter
#define EPB (NE / NBLK)          // 6250 edges per block
#define NBINS 782                // ceil(NN/128) coarse bins of 128 nodes
#define NCELL (NBINS * NBLK)     // 200192 scan cells
#define NSB ((NCELL + 1023) / 1024)  // 196 scan blocks
#define GEMMB 1563               // gemm blocks: 64 rows per block
#define BINCAP 4096              // LDS staging per bin (mean bin count 2046, sd ~45)
#define SMEM_BYTES (BINCAP * 4 + 3 * 128 * 4)   // 17920 B; also >= 64*65*4 = 16640

// ---------------- bf16 helpers ----------------

__device__ __forceinline__ unsigned pack_bf16(float a, float b) {
    unsigned ua = __float_as_uint(a);
    unsigned ub = __float_as_uint(b);
    ua += 0x7FFFu + ((ua >> 16) & 1u);       // RNE
    ub += 0x7FFFu + ((ub >> 16) & 1u);
    return (ua >> 16) | (ub & 0xFFFF0000u);  // a -> low half (element 2k)
}
#define BF_LO(u) __uint_as_float((u) << 16)
#define BF_HI(u) __uint_as_float((u) & 0xFFFF0000u)

// ---------------- edge_index width detection, inlined ----------------------

__device__ __forceinline__ int ei_is64(const int* __restrict__ ei) {
    int z = 0;
#pragma unroll
    for (int i = 0; i < 16; ++i) z |= ei[2 * i + 1];
    return z == 0;
}

// ---------------- CSR build via 2-level counting sort (NO global atomics) ----
// R4: global atomic-return fill = 160us (coherence serialization). R8: fused
// grid-barrier build = 126us (cross-XCD spin). Split 4-kernel counting sort
// is the verified design.

__global__ void __launch_bounds__(1024) k_hist(const int* __restrict__ ei,
                                               int* __restrict__ gcount) {
    __shared__ int lbin[NBINS];
    int t = threadIdx.x, blk = blockIdx.x;
    for (int i = t; i < NBINS; i += 1024) lbin[i] = 0;
    __syncthreads();
    int is64 = ei_is64(ei);
    int e0 = blk * EPB;
    if (is64) {
        const int2* p = (const int2*)ei;
        for (int e = e0 + t; e < e0 + EPB; e += 1024)
            atomicAdd(&lbin[p[NE + e].x >> 7], 1);
    } else {
        for (int e = e0 + t; e < e0 + EPB; e += 1024)
            atomicAdd(&lbin[ei[NE + e] >> 7], 1);
    }
    __syncthreads();
    for (int b = t; b < NBINS; b += 1024) gcount[b * NBLK + blk] = lbin[b];
}

__global__ void k_pscan1(const int* __restrict__ g, int* __restrict__ bsum) {
    __shared__ int sh[256];
    int t = threadIdx.x;
    int base = blockIdx.x * 1024 + t * 4;
    int s = 0;
#pragma unroll
    for (int j = 0; j < 4; ++j) { int i = base + j; if (i < NCELL) s += g[i]; }
    sh[t] = s; __syncthreads();
    for (int off = 128; off > 0; off >>= 1) {
        if (t < off) sh[t] += sh[t + off];
        __syncthreads();
    }
    if (t == 0) bsum[blockIdx.x] = sh[0];
}

// pscan2 fused into pscan3: each block redundantly scans the 196 block sums
// (784 B, trivial) to find its own offset -> one fewer dependent launch.
__global__ void k_pscan23(const int* __restrict__ g, const int* __restrict__ bsum,
                          int* __restrict__ goff) {
    __shared__ int sh[256];
    __shared__ int boffs;
    int t = threadIdx.x;
    int bv = (t < NSB) ? bsum[t] : 0;
    sh[t] = bv; __syncthreads();
    for (int off = 1; off < 256; off <<= 1) {
        int tmp = (t >= off) ? sh[t - off] : 0;
        __syncthreads();
        sh[t] += tmp;
        __syncthreads();
    }
    if (t == blockIdx.x) boffs = sh[t] - bv;   // exclusive prefix of own block
    __syncthreads();
    int base = blockIdx.x * 1024 + t * 4;
    int v[4]; int s = 0;
#pragma unroll
    for (int j = 0; j < 4; ++j) { int i = base + j; v[j] = (i < NCELL) ? g[i] : 0; s += v[j]; }
    __syncthreads();                           // sh reuse safe (scan loop done)
    sh[t] = s; __syncthreads();
    for (int off = 1; off < 256; off <<= 1) {
        int tmp = (t >= off) ? sh[t - off] : 0;
        __syncthreads();
        sh[t] += tmp;
        __syncthreads();
    }
    int run = sh[t] - s + boffs;
#pragma unroll
    for (int j = 0; j < 4; ++j) {
        int i = base + j;
        if (i < NCELL) { goff[i] = run; run += v[j]; }
    }
}

// ---------------- scatter, R13-verified: two-phase LDS-sorted, ORDERED writes
// (was 6x write amplification from 64 scattered 4B partial lines per store;
// ordered pass emits each cell's ~8 entries as one 32B run). R13: -12us.
// tmp entry: src (17 bits) | d_low7 << 17.

__global__ void __launch_bounds__(1024) k_scatter(const int* __restrict__ ei,
                                                  const int* __restrict__ gcount,
                                                  const int* __restrict__ goff,
                                                  unsigned* __restrict__ tmp) {
    __shared__ int gbase[NBINS];
    __shared__ int lofs[NBINS];
    __shared__ int lcur[NBINS];
    __shared__ int sc[1024];
    __shared__ uint2 buf[EPB];      // 50 KB; total LDS 63.5 KB, 2 blocks/CU
    int t = threadIdx.x, blk = blockIdx.x;
    int c = 0;
    if (t < NBINS) {
        c = gcount[t * NBLK + blk];
        gbase[t] = goff[t * NBLK + blk];
    }
    sc[t] = c;
    __syncthreads();
    for (int off = 1; off < 1024; off <<= 1) {     // inclusive scan, 1 thr/bin
        int v = (t >= off) ? sc[t - off] : 0;
        __syncthreads();
        sc[t] += v;
        __syncthreads();
    }
    if (t < NBINS) {
        int ex = sc[t] - c;        // exclusive prefix = this bin's local base
        lofs[t] = ex;
        lcur[t] = ex;
    }
    __syncthreads();
    int is64 = ei_is64(ei);
    int e0 = blk * EPB;
    for (int e = e0 + t; e < e0 + EPB; e += 1024) {
        int s, d;
        if (is64) {
            s = ((const int2*)ei)[e].x;
            d = ((const int2*)ei)[NE + e].x;
        } else {
            s = ei[e];
            d = ei[NE + e];
        }
        int b = d >> 7;
        int li = atomicAdd(&lcur[b], 1);
        unsigned pos = (unsigned)(gbase[b] + (li - lofs[b]));
        buf[li] = make_uint2(pos, (unsigned)s | ((unsigned)(d & 127) << 17));
    }
    __syncthreads();
    for (int i = t; i < EPB; i += 1024)            // ordered write pass
        tmp[buf[i].x] = buf[i].y;
}

// ---------------- fp32 GEMM -> bf16 H: H[N,64] = X[N,64] @ W[64,64] ----------
// R11-verified: lane=row compute mapping (wave-uniform W -> s_load, acc[] in
// VGPRs) + X tile staged through LDS with one coalesced block load, padded
// [64][65] so per-lane row reads are bank-rotated conflict-free. Block =
// 4 waves = 4 column-quarters of one 64-row tile. Bit-identical k-order.

__device__ __forceinline__ void gemm_body(int gb, const float* __restrict__ X,
                                          const float* __restrict__ W,
                                          unsigned* __restrict__ Hb,
                                          float* xt) {
    int t = threadIdx.x;
    int lane = t & 63;
    int wv = t >> 6;                      // column quarter 0..3
    int rbase = gb * 64;
    const float4* xg = (const float4*)X;
#pragma unroll
    for (int j = 0; j < 4; ++j) {
        int idx = j * 256 + t;            // 0..1023 = 64 rows x 16 float4
        int row = idx >> 4;
        int q = idx & 15;
        int gr = rbase + row;
        int r = gr < NN ? gr : NN - 1;    // clamped rows stage duplicate data
        float4 v = xg[(size_t)r * 16 + q];
        float* dst = xt + row * 65 + q * 4;
        dst[0] = v.x; dst[1] = v.y; dst[2] = v.z; dst[3] = v.w;
    }
    __syncthreads();
    int grow = rbase + lane;
    int r = grow < NN ? grow : NN - 1;
    int ch = __builtin_amdgcn_readfirstlane(wv);   // scalar -> W via s_load
    const float* Wb = W + ch * 16;                 // columns ch*16 .. ch*16+15
    const float* xr = xt + lane * 65;
    float acc[16];
#pragma unroll
    for (int c = 0; c < 16; ++c) acc[c] = 0.f;
#pragma unroll 4
    for (int k4 = 0; k4 < 16; ++k4) {
#pragma unroll
        for (int kj = 0; kj < 4; ++kj) {
            float xk = xr[k4 * 4 + kj];
            const float4* wr = (const float4*)(Wb + (k4 * 4 + kj) * 64);
#pragma unroll
            for (int c4 = 0; c4 < 4; ++c4) {
                float4 wv4 = wr[c4];
                acc[c4 * 4 + 0] += xk * wv4.x;
                acc[c4 * 4 + 1] += xk * wv4.y;
                acc[c4 * 4 + 2] += xk * wv4.z;
                acc[c4 * 4 + 3] += xk * wv4.w;
            }
        }
    }
    // store 16 bf16 = 8 words = 2 uint4 at row base + quarter offset
    uint4* op = (uint4*)(Hb + (size_t)r * 32 + ch * 8);
#pragma unroll
    for (int q = 0; q < 2; ++q) {
        uint4 o;
        o.x = pack_bf16(acc[q * 8 + 0], acc[q * 8 + 1]);
        o.y = pack_bf16(acc[q * 8 + 2], acc[q * 8 + 3]);
        o.z = pack_bf16(acc[q * 8 + 4], acc[q * 8 + 5]);
        o.w = pack_bf16(acc[q * 8 + 6], acc[q * 8 + 7]);
        op[q] = o;
    }
}

__global__ void __launch_bounds__(256) k_gemm(const float* __restrict__ X,
                                              const float* __restrict__ W,
                                              unsigned* __restrict__ Hb) {
    __shared__ __align__(16) char smem[SMEM_BYTES];
    gemm_body(blockIdx.x, X, W, Hb, (float*)smem);
}

// ---------------- fused deg+csr + gemm1, R15: ORDERED csr writes ------------
// Blocks [0,NBINS): finalize CSR for one 128-node bin. R15 applies the R13
// scatter trick here: the old per-edge csr store was 64 scattered addresses
// per instruction (TA-serialized). Now phase 3 scatters entries into an LDS
// buffer SORTED BY NODE (sbuf[loff[dl]+lr], replacing the old read-cache —
// the 8KB tmp slice is L2-hot from phase 1, so the re-read is ~free), and
// phase 4 writes csr[bs+i] = sbuf[i] fully coalesced. Same position set and
// (already nondeterministic) within-node order -> numerics unchanged.
// Blocks [NBINS,NBINS+GEMMB): layer-1 GEMM co-launched (common consumer).

__global__ void __launch_bounds__(256) k_degcsr_gemm(const unsigned* __restrict__ tmp,
                                                     const int* __restrict__ goff,
                                                     int* __restrict__ rs,
                                                     float* __restrict__ dinv,
                                                     unsigned* __restrict__ csr,
                                                     const float* __restrict__ X,
                                                     const float* __restrict__ W1,
                                                     unsigned* __restrict__ Hb) {
    __shared__ __align__(16) char smem[SMEM_BYTES];
    if (blockIdx.x >= NBINS) {
        gemm_body((int)blockIdx.x - NBINS, X, W1, Hb, (float*)smem);
        return;
    }
    unsigned* sbuf   = (unsigned*)smem;            // node-sorted staging
    int*      hist   = (int*)(smem + BINCAP * 4);
    int*      cur    = hist + 128;
    int*      lofs   = cur + 128;                  // local (in-bin) offsets
    int b = blockIdx.x, t = threadIdx.x;
    if (t < 128) { hist[t] = 0; cur[t] = 0; }
    __syncthreads();
    int bs = goff[b * NBLK];
    int be = (b == NBINS - 1) ? NE : goff[(b + 1) * NBLK];
    for (int e = bs + t; e < be; e += 256)
        atomicAdd(&hist[tmp[e] >> 17], 1);
    __syncthreads();
    if (t < 128) {
        int node = b * 128 + t;
        if (node < NN) {
            int c = hist[t];
            int loff = 0;
            for (int i = 0; i < t; ++i) loff += hist[i];
            rs[node] = bs + loff;
            lofs[t] = loff;
            dinv[node] = rsqrtf((float)c + 1.0f);
        } else lofs[t] = 0;
    }
    if (b == 0 && t == 0) rs[NN] = NE;
    __syncthreads();
    for (int e = bs + t; e < be; e += 256) {       // tmp slice L2-hot re-read
        unsigned v = tmp[e];
        int dl = v >> 17;
        int lr = atomicAdd(&cur[dl], 1);
        int li = lofs[dl] + lr;
        unsigned sv = v & 0x1FFFFu;                // plain src id
        if (li < BINCAP) sbuf[li] = sv;
        else csr[bs + li] = sv;                    // overflow fallback (~45sigma)
    }
    __syncthreads();
    int cnt = be - bs;
    int lim = cnt < BINCAP ? cnt : BINCAP;
    for (int i = t; i < lim; i += 256)             // ordered coalesced write
        csr[bs + i] = sbuf[i];
}

// ---------------- aggregation: TWO nodes per wave (R11-verified, FROZEN) ----
// R6 (uint2), R7 (per-lane fused gemm), R12 (batch-16 masking), R14 (block-
// parallel fused gemm: barrier couples waves to slowest node, 3x slower) all
// regressed — this structure is converged and tolerates NO appended phases:
// half-wave h owns node 2*wid+h, 4 edge groups x 8 feature lanes, uint4 16B
// gathers, 2-deep csr pipeline, 2-level reduce.

#define EDGE_ACC(wt, r)                                                       \
    {                                                                         \
        a0 += BF_LO((r).x) * (wt); a1 += BF_HI((r).x) * (wt);                 \
        a2 += BF_LO((r).y) * (wt); a3 += BF_HI((r).y) * (wt);                 \
        a4 += BF_LO((r).z) * (wt); a5 += BF_HI((r).z) * (wt);                 \
        a6 += BF_LO((r).w) * (wt); a7 += BF_HI((r).w) * (wt);                 \
    }

__global__ void __launch_bounds__(256) k_agg(const unsigned* __restrict__ hb,
                                             const int* __restrict__ rs,
                                             const unsigned* __restrict__ csr,
                                             const float* __restrict__ dinv,
                                             const float* __restrict__ bias,
                                             float4* __restrict__ out4) {
    int wid = (blockIdx.x * blockDim.x + threadIdx.x) >> 6;
    int lane = threadIdx.x & 63;
    int node = wid * 2 + (lane >> 5);          // half-wave owns one node
    if (node >= NN) return;
    int g = (lane >> 3) & 3;  // edge-stream group 0..3 within half-wave
    int s = lane & 7;         // feature octet 0..7
    const char* hbc = (const char*)hb;
    const char* dvc = (const char*)dinv;
    unsigned soff = (unsigned)s << 4;
    float dn = dinv[node];
    int e0 = rs[node], e1 = rs[node + 1];
    float a0 = 0.f, a1 = 0.f, a2 = 0.f, a3 = 0.f;
    float a4 = 0.f, a5 = 0.f, a6 = 0.f, a7 = 0.f;
    int e = e0 + g;
    unsigned p0 = csr[e];
    unsigned p1 = csr[e + 4];
    for (; e + 4 < e1; e += 8) {
        unsigned q0 = csr[e + 8];
        unsigned q1 = csr[e + 12];
        float w0 = *(const float*)(dvc + (size_t)(p0 << 2));
        float w1 = *(const float*)(dvc + (size_t)(p1 << 2));
        uint4 r0 = *(const uint4*)(hbc + (size_t)((p0 << 7) + soff));
        uint4 r1 = *(const uint4*)(hbc + (size_t)((p1 << 7) + soff));
        EDGE_ACC(w0, r0);
        EDGE_ACC(w1, r1);
        p0 = q0; p1 = q1;
    }
    if (e < e1) {
        float w0 = *(const float*)(dvc + (size_t)(p0 << 2));
        uint4 r0 = *(const uint4*)(hbc + (size_t)((p0 << 7) + soff));
        EDGE_ACC(w0, r0);
    }
    // reduce across the 4 groups (lane bits 3,4) — stays within half-wave
#pragma unroll
    for (int m = 8; m <= 16; m <<= 1) {
        a0 += __shfl_xor(a0, m); a1 += __shfl_xor(a1, m);
        a2 += __shfl_xor(a2, m); a3 += __shfl_xor(a3, m);
        a4 += __shfl_xor(a4, m); a5 += __shfl_xor(a5, m);
        a6 += __shfl_xor(a6, m); a7 += __shfl_xor(a7, m);
    }
    if ((lane & 31) < 8) {
        uint4 r = *(const uint4*)(hbc + (size_t)(((unsigned)node << 7) + soff));
        const float4* bp = (const float4*)(bias + s * 8);
        float4 b0 = bp[0], b1v = bp[1];
        float4 o0, o1;
        o0.x = fmaxf((a0 + BF_LO(r.x) * dn) * dn + b0.x, 0.f);
        o0.y = fmaxf((a1 + BF_HI(r.x) * dn) * dn + b0.y, 0.f);
        o0.z = fmaxf((a2 + BF_LO(r.y) * dn) * dn + b0.z, 0.f);
        o0.w = fmaxf((a3 + BF_HI(r.y) * dn) * dn + b0.w, 0.f);
        o1.x = fmaxf((a4 + BF_LO(r.z) * dn) * dn + b1v.x, 0.f);
        o1.y = fmaxf((a5 + BF_HI(r.z) * dn) * dn + b1v.y, 0.f);
        o1.z = fmaxf((a6 + BF_LO(r.w) * dn) * dn + b1v.z, 0.f);
        o1.w = fmaxf((a7 + BF_HI(r.w) * dn) * dn + b1v.w, 0.f);
        out4[(size_t)node * 16 + s * 2] = o0;
        out4[(size_t)node * 16 + s * 2 + 1] = o1;
    }
}

// ---------------- launch ----------------

extern "C" void kernel_launch(void* const* d_in, const int* in_sizes, int n_in,
                              void* d_out, int out_size, void* d_ws, size_t ws_size,
                              hipStream_t stream) {
    const float* x  = (const float*)d_in[0];            // [NN,64] fp32
    const int* ei   = (const int*)d_in[1];              // [2,NE] int32/int64 (detected)
    const float* W1 = (const float*)d_in[2];
    const float* b1 = (const float*)d_in[3];
    const float* W2 = (const float*)d_in[4];
    const float* b2 = (const float*)d_in[5];

    char* ws = (char*)d_ws;
    size_t off = 0;
    auto alloc = [&](size_t bytes) -> char* {
        char* p = ws + off;
        off = (off + bytes + 511) & ~(size_t)511;
        return p;
    };
    int*      gcount= (int*)alloc((size_t)NCELL * 4);    // 800 KB
    int*      goff  = (int*)alloc((size_t)NCELL * 4);    // 800 KB
    int*      bsum  = (int*)alloc((size_t)NSB * 4);
    unsigned* tmp   = (unsigned*)alloc((size_t)NE * 4);  // 6.4 MB
    unsigned* csr   = (unsigned*)alloc((size_t)NE * 4);  // 6.4 MB
    int*      rs    = (int*)alloc((size_t)(NN + 1) * 4);
    float*    dinv  = (float*)alloc((size_t)NN * 4);
    unsigned* hbuf  = (unsigned*)alloc((size_t)NN * 32 * 4);  // 12.8 MB bf16 h (128 B rows)
    float*    hmid  = (float*)d_out;                     // layer-1 fp32 act (reuse d_out)

    k_hist<<<NBLK, 1024, 0, stream>>>(ei, gcount);
    k_pscan1<<<NSB, 256, 0, stream>>>(gcount, bsum);
    k_pscan23<<<NSB, 256, 0, stream>>>(gcount, bsum, goff);
    k_scatter<<<NBLK, 1024, 0, stream>>>(ei, gcount, goff, tmp);
    // CSR finalize + layer-1 GEMM co-launched (independent work, common consumer)
    k_degcsr_gemm<<<NBINS + GEMMB, 256, 0, stream>>>(tmp, goff, rs, dinv, csr,
                                                     x, W1, hbuf);
    // layer 1: hmid(=d_out, fp32) = relu(agg(hbuf) + b1)  [2 nodes/wave]
    k_agg<<<(NN / 2) * 64 / 256, 256, 0, stream>>>(hbuf, rs, csr, dinv, b1,
                                                   (float4*)hmid);
    // layer 2: hbuf(bf16) = hmid @ W2 ; d_out = relu(agg(hbuf) + b2)
    k_gemm<<<GEMMB, 256, 0, stream>>>(hmid, W2, hbuf);
    k_agg<<<(NN / 2) * 64 / 256, 256, 0, stream>>>(hbuf, rs, csr, dinv, b2,
                                                   (float4*)d_out);
}